// Round 1
// baseline (1041.204 us; speedup 1.0000x reference)
//
#include <hip/hip_runtime.h>
#include <hip/hip_bf16.h>

#define TSEQ 1024
#define NB   128
#define HID  128
#define QDIM 16

typedef unsigned int  u32;
typedef unsigned short u16;

// ---------------- cross-lane helpers (wave64) ----------------

template<int CTRL>
__device__ __forceinline__ int dpp_i(int x) {
  return __builtin_amdgcn_update_dpp(0, x, CTRL, 0xF, 0xF, true);
}
template<int CTRL>
__device__ __forceinline__ float dpp_f(float x) {
  return __int_as_float(dpp_i<CTRL>(__float_as_int(x)));
}

#ifdef __has_builtin
#if __has_builtin(__builtin_amdgcn_permlane16_swap) && __has_builtin(__builtin_amdgcn_permlane32_swap)
#define HAS_PLS 1
#endif
#endif
#ifndef HAS_PLS
#define HAS_PLS 0
#endif

// x + x[lane^16]  (valid in every lane)
__device__ __forceinline__ float x16_sum(float x) {
#if HAS_PLS
  auto r = __builtin_amdgcn_permlane16_swap(__float_as_uint(x), __float_as_uint(x), false, false);
  return __uint_as_float(r[0]) + __uint_as_float(r[1]);
#else
  return x + __shfl_xor(x, 16, 64);
#endif
}
// x + x[lane^32]
__device__ __forceinline__ float x32_sum(float x) {
#if HAS_PLS
  auto r = __builtin_amdgcn_permlane32_swap(__float_as_uint(x), __float_as_uint(x), false, false);
  return __uint_as_float(r[0]) + __uint_as_float(r[1]);
#else
  return x + __shfl_xor(x, 32, 64);
#endif
}
// sum over the 16-lane row; every lane of the row gets the total.
__device__ __forceinline__ float row16_sum(float x) {
  x += dpp_f<0xB1>(x);   // quad_perm(1,0,3,2): xor 1
  x += dpp_f<0x4E>(x);   // quad_perm(2,3,0,1): xor 2
  x += dpp_f<0x124>(x);  // row_ror:4  (rotation-invariant sum)
  x += dpp_f<0x128>(x);  // row_ror:8
  return x;
}
__device__ __forceinline__ float rcpf(float x) { return __builtin_amdgcn_rcpf(x); }
__device__ __forceinline__ u16 f2bf(float f) {
  u32 u = __float_as_uint(f);
  u32 r = (u + 0x7FFFu + ((u >> 16) & 1u)) >> 16;
  return (u16)r;
}

#define ROTS_L(X) X(1) X(2) X(3) X(4) X(5) X(6) X(7)
#define ROTS_H(X) X(8) X(9) X(10) X(11) X(12) X(13) X(14) X(15)
#define ROTS_ALL(X) ROTS_L(X) ROTS_H(X)

// padded LDS index for h / rh vectors: chunk r of 32 floats starts at r*36
__device__ __forceinline__ int padidx(int m) { return (m >> 5) * 36 + (m & 31); }

// ---------------- kernel 1: xw[b,t,j] = x[b,t,:] @ W_x + b_in ----------------

__global__ __launch_bounds__(256) void xw_kernel(
    const float* __restrict__ x, const float* __restrict__ W_in,
    const float* __restrict__ b_in, float* __restrict__ xw) {
  __shared__ __align__(16) float xs[16][132];   // 132 stride breaks bank aliasing; 528B rows keep float4 alignment
  __shared__ float wl[2048];
  __shared__ float bl[16];
  const int tid = threadIdx.x;
  const long r0 = (long)blockIdx.x * 16;
#pragma unroll
  for (int i = 0; i < 8; ++i) {
    int idx = tid + i * 256;
    xs[idx >> 7][idx & 127] = x[(r0 + (idx >> 7)) * 128 + (idx & 127)];
  }
#pragma unroll
  for (int i = 0; i < 8; ++i) {
    int idx = tid + i * 256;
    wl[idx] = W_in[2048 + idx];   // W_x = W_in[128:256, :]
  }
  if (tid < 16) bl[tid] = b_in[tid];
  __syncthreads();
  const int rr = tid >> 4, j = tid & 15;
  float s = bl[j];
#pragma unroll
  for (int k4 = 0; k4 < 32; ++k4) {
    float4 v = *reinterpret_cast<const float4*>(&xs[rr][k4 * 4]);
    int kb = k4 * 4;
    s = fmaf(v.x, wl[(kb + 0) * 16 + j], s);
    s = fmaf(v.y, wl[(kb + 1) * 16 + j], s);
    s = fmaf(v.z, wl[(kb + 2) * 16 + j], s);
    s = fmaf(v.w, wl[(kb + 3) * 16 + j], s);
  }
  xw[(r0 + rr) * 16 + j] = s;
}

// ---------------- kernel 2: the recurrence. 256 blocks x 64 threads ----------------
// block = one (direction, batch-row). lane layout: row = tid>>4 (4 rows), col = tid&15.

template<bool BF16WS>
__global__ __launch_bounds__(64) void qbigru_main(
    const float* __restrict__ W_in,
    const float* __restrict__ W_out,
    const float* __restrict__ b_out,
    const float* __restrict__ thr_f, const float* __restrict__ thr1_f, const float* __restrict__ thu_f,
    const float* __restrict__ thr_b, const float* __restrict__ thr1_b, const float* __restrict__ thu_b,
    const float* __restrict__ xw,
    float* __restrict__ out,
    void* __restrict__ bwdws) {
  const int tid = threadIdx.x;
  const int row = tid >> 4;
  const int col = tid & 15;
  const int dir = blockIdx.x >> 7;
  const int b   = blockIdx.x & 127;

  __shared__ __align__(16) float h_lds[144];
  __shared__ __align__(16) float rh_lds[144];
  __shared__ int sinv[16];

  // sigma^{-1}: psi_after_CNOTs[v] = psi0[sigma(v)]; sigma = F1∘...∘F8 applied g8-first.
  if (tid < 16) {
    int u = tid;
#define APPLY(c, t) u ^= (((u >> (3 - (c))) & 1) << (3 - (t)));
    APPLY(3, 1) APPLY(2, 0) APPLY(1, 3) APPLY(0, 2)
    APPLY(3, 0) APPLY(2, 3) APPLY(1, 2) APPLY(0, 1)
#undef APPLY
    sinv[u] = tid;
  }
  const int i0 = padidx(tid);
  const int i1 = padidx(tid + 64);
  h_lds[i0] = 0.f;
  h_lds[i1] = 0.f;
  __syncthreads();

  // rotation-index table: ri[c][lane] = col of the lane that row_ror:c sources from.
  int ri[16];
  ri[0] = col;
#define RIX(c) ri[c] = dpp_i<(0x120 | c)>(col);
  ROTS_ALL(RIX)
#undef RIX

  // ---- per-lane constant coefficients ----
  const float* thr  = dir ? thr_b  : thr_f;
  const float* thr1 = dir ? thr1_b : thr1_f;
  const float* thu  = dir ? thu_b  : thu_f;
  const float* thA  = (row < 2) ? thr : thu;   // rows 0,1 -> reset VQC; rows 2,3 -> update VQC
  float ch[4], sh[4], ch2[4], sh2[4];
#pragma unroll
  for (int i = 0; i < 4; ++i) {
    float a = 0.5f * thA[i];   ch[i]  = cosf(a);  sh[i]  = sinf(a);
    float a2 = 0.5f * thr1[i]; ch2[i] = cosf(a2); sh2[i] = sinf(a2);
  }
  const bool isIm = (row & 1);
  // mc1/mc2[c] = (Re|Im) U[s=col, sinv[ri[c]]]  for the two theta sets
  float mc1[16], mc2[16];
#pragma unroll
  for (int c = 0; c < 16; ++c) {
    int j = ri[c];
    int t = sinv[j];
    int d = col ^ t;
    int b3 = (d >> 3) & 1, b2v = (d >> 2) & 1, b1v = (d >> 1) & 1, b0v = d & 1;
    float mag  = (b3 ? sh[0]  : ch[0])  * (b2v ? sh[1]  : ch[1])  * (b1v ? sh[2]  : ch[2])  * (b0v ? sh[3]  : ch[3]);
    float mag2 = (b3 ? sh2[0] : ch2[0]) * (b2v ? sh2[1] : ch2[1]) * (b1v ? sh2[2] : ch2[2]) * (b0v ? sh2[3] : ch2[3]);
    int p = __popc(d) & 3;   // (-i)^p : 0->(1,0) 1->(0,-1) 2->(-1,0) 3->(0,1)
    float re  = (p == 0) ?  mag  : (p == 2) ? -mag  : 0.f;
    float im  = (p == 1) ? -mag  : (p == 3) ?  mag  : 0.f;
    float re2 = (p == 0) ?  mag2 : (p == 2) ? -mag2 : 0.f;
    float im2 = (p == 1) ? -mag2 : (p == 3) ?  mag2 : 0.f;
    mc1[c] = isIm ? im  : re;
    mc2[c] = isIm ? im2 : re2;
  }

  // G = Z @ W_out  (16 x 128), per lane the columns m=tid and m=tid+64, in ri-rotated s order
  float G1[16], G2[16];
  {
    float wo0[4], wo1[4];
#pragma unroll
    for (int w = 0; w < 4; ++w) {
      wo0[w] = W_out[w * HID + tid];
      wo1[w] = W_out[w * HID + tid + 64];
    }
#pragma unroll
    for (int c = 0; c < 16; ++c) {
      int s = ri[c];
      float g0 = 0.f, g1 = 0.f;
#pragma unroll
      for (int w = 0; w < 4; ++w) {
        float zz = ((s >> (3 - w)) & 1) ? -1.f : 1.f;
        g0 += zz * wo0[w];
        g1 += zz * wo1[w];
      }
      G1[c] = g0; G2[c] = g1;
    }
  }
  const float bout0 = b_out[tid];
  const float bout1 = b_out[tid + 64];

  // W_h slice: k = row*32 .. row*32+31, column = col
  float wc[32];
#pragma unroll
  for (int kk = 0; kk < 32; ++kk)
    wc[kk] = W_in[(row * 32 + kk) * QDIM + col];

  float h0 = 0.f, h1 = 0.f;
  int tt0 = dir ? (TSEQ - 1) : 0;
  float xw_cur = xw[((long)b * TSEQ + tt0) * QDIM + col];

  for (int t = 0; t < TSEQ; ++t) {
    // prefetch next step's xw (consumed next iteration -> latency hidden; no barriers drain vmcnt)
    int tn  = (t + 1 < TSEQ) ? (t + 1) : t;
    int ttn = dir ? (TSEQ - 1 - tn) : tn;
    float xw_nxt = xw[((long)b * TSEQ + ttn) * QDIM + col];

    // ---- y = h @ W_h + (x@W_x + b_in) ----
    const float* hrow = &h_lds[row * 36];
    float a0 = 0.f, a1 = 0.f, a2 = 0.f, a3 = 0.f;
#pragma unroll
    for (int q = 0; q < 8; ++q) {
      float4 v = *reinterpret_cast<const float4*>(hrow + q * 4);
      a0 = fmaf(v.x, wc[q * 4 + 0], a0);
      a1 = fmaf(v.y, wc[q * 4 + 1], a1);
      a2 = fmaf(v.z, wc[q * 4 + 2], a2);
      a3 = fmaf(v.w, wc[q * 4 + 3], a3);
    }
    float y = x16_sum(x32_sum((a0 + a1) + (a2 + a3))) + xw_cur;   // y[col], replicated over rows

    float n2  = row16_sum(y * y);
    float inv = rcpf(n2);

    // amp = (A|B)_set y ; row0:Re_r row1:Im_r row2:Re_u row3:Im_u, s = col
    float A0 = mc1[0] * y, A1 = 0.f;
#define MV1L(c) A0 = fmaf(mc1[c], dpp_f<(0x120 | c)>(y), A0);
#define MV1H(c) A1 = fmaf(mc1[c], dpp_f<(0x120 | c)>(y), A1);
    ROTS_L(MV1L) ROTS_H(MV1H)
#undef MV1L
#undef MV1H
    float amp = A0 + A1;
    float sq = amp * amp;
    float pairv = x16_sum(sq);        // rows0,1: probs_r[col]; rows2,3: probs_u[col]
    float other = x32_sum(pairv) - pairv;
    float pr = (tid < 32) ? pairv : other;
    float pu = (tid < 32) ? other : pairv;

    // gate pre-activations: (probs . G[:,m]) * inv + b_out
    float rd0 = G1[0] * pr, rd1 = G2[0] * pr, zd0 = G1[0] * pu, zd1 = G2[0] * pu;
#define GDOT(c) { float prr = dpp_f<(0x120 | c)>(pr); float pur = dpp_f<(0x120 | c)>(pu); \
                  rd0 = fmaf(G1[c], prr, rd0); rd1 = fmaf(G2[c], prr, rd1); \
                  zd0 = fmaf(G1[c], pur, zd0); zd1 = fmaf(G2[c], pur, zd1); }
    ROTS_ALL(GDOT)
#undef GDOT
    float r0 = rcpf(1.f + __expf(-(rd0 * inv + bout0)));
    float r1 = rcpf(1.f + __expf(-(rd1 * inv + bout1)));
    float z0 = rcpf(1.f + __expf(-(zd0 * inv + bout0)));
    float z1 = rcpf(1.f + __expf(-(zd1 * inv + bout1)));

    rh_lds[i0] = r0 * h0;
    rh_lds[i1] = r1 * h1;
    asm volatile("" ::: "memory");   // single wave: DS pipe is in-order; just stop compiler reordering

    // ---- v1 = (r*h) @ W_h + xw ----
    const float* rrow = &rh_lds[row * 36];
    float c0 = 0.f, c1 = 0.f, c2 = 0.f, c3 = 0.f;
#pragma unroll
    for (int q = 0; q < 8; ++q) {
      float4 v = *reinterpret_cast<const float4*>(rrow + q * 4);
      c0 = fmaf(v.x, wc[q * 4 + 0], c0);
      c1 = fmaf(v.y, wc[q * 4 + 1], c1);
      c2 = fmaf(v.z, wc[q * 4 + 2], c2);
      c3 = fmaf(v.w, wc[q * 4 + 3], c3);
    }
    float vv = x16_sum(x32_sum((c0 + c1) + (c2 + c3))) + xw_cur;
    float n2b  = row16_sum(vv * vv);
    float invb = rcpf(n2b);
    float B0v = mc2[0] * vv, B1v = 0.f;
#define MV2L(c) B0v = fmaf(mc2[c], dpp_f<(0x120 | c)>(vv), B0v);
#define MV2H(c) B1v = fmaf(mc2[c], dpp_f<(0x120 | c)>(vv), B1v);
    ROTS_L(MV2L) ROTS_H(MV2H)
#undef MV2L
#undef MV2H
    float amp2 = B0v + B1v;
    float p1 = x16_sum(amp2 * amp2);  // probs_r1[col] in every lane (rows 2,3 duplicate rows 0,1)
    float hd0 = G1[0] * p1, hd1 = G2[0] * p1;
#define HDOT(c) { float p1r = dpp_f<(0x120 | c)>(p1); hd0 = fmaf(G1[c], p1r, hd0); hd1 = fmaf(G2[c], p1r, hd1); }
    ROTS_ALL(HDOT)
#undef HDOT
    float e0 = __expf(2.f * (hd0 * invb + bout0));
    float e1 = __expf(2.f * (hd1 * invb + bout1));
    float h2_0 = 1.f - 2.f * rcpf(e0 + 1.f);   // tanh, graceful at overflow
    float h2_1 = 1.f - 2.f * rcpf(e1 + 1.f);

    float hn0 = h0 + z0 * (h2_0 - h0);
    float hn1 = h1 + z1 * (h2_1 - h1);

    long oidx = ((long)b * TSEQ + t) * HID + tid;
    if (dir == 0) {
      out[oidx]      = 0.5f * hn0;
      out[oidx + 64] = 0.5f * hn1;
    } else {
      if (BF16WS) {
        u16* bw = (u16*)bwdws;
        bw[oidx]      = f2bf(0.5f * hn0);
        bw[oidx + 64] = f2bf(0.5f * hn1);
      } else {
        float* bw = (float*)bwdws;
        bw[oidx]      = 0.5f * hn0;
        bw[oidx + 64] = 0.5f * hn1;
      }
    }

    h0 = hn0; h1 = hn1;
    h_lds[i0] = hn0;
    h_lds[i1] = hn1;
    asm volatile("" ::: "memory");
    xw_cur = xw_nxt;
  }
}

// ---------------- kernel 3: out += bwd trajectory ----------------

template<bool BF16WS>
__global__ __launch_bounds__(256) void combine_k(float* __restrict__ out,
                                                 const void* __restrict__ bwd, long n4) {
  long i = (long)blockIdx.x * 256 + threadIdx.x;
  const long stride = (long)gridDim.x * 256;
  for (; i < n4; i += stride) {
    float4 o = reinterpret_cast<float4*>(out)[i];
    float ax, ay, az, aw;
    if (BF16WS) {
      ushort4 u = reinterpret_cast<const ushort4*>(bwd)[i];
      ax = __uint_as_float((u32)u.x << 16);
      ay = __uint_as_float((u32)u.y << 16);
      az = __uint_as_float((u32)u.z << 16);
      aw = __uint_as_float((u32)u.w << 16);
    } else {
      float4 a = reinterpret_cast<const float4*>(bwd)[i];
      ax = a.x; ay = a.y; az = a.z; aw = a.w;
    }
    o.x += ax; o.y += ay; o.z += az; o.w += aw;
    reinterpret_cast<float4*>(out)[i] = o;
  }
}

// ---------------- launch ----------------

extern "C" void kernel_launch(void* const* d_in, const int* in_sizes, int n_in,
                              void* d_out, int out_size, void* d_ws, size_t ws_size,
                              hipStream_t stream) {
  const float* x     = (const float*)d_in[0];
  const float* W_in  = (const float*)d_in[1];
  const float* b_in  = (const float*)d_in[2];
  const float* W_out = (const float*)d_in[3];
  const float* b_out = (const float*)d_in[4];
  const float* thr_f  = (const float*)d_in[5];
  const float* thr1_f = (const float*)d_in[6];
  const float* thu_f  = (const float*)d_in[7];
  const float* thr_b  = (const float*)d_in[8];
  const float* thr1_b = (const float*)d_in[9];
  const float* thu_b  = (const float*)d_in[10];
  float* out = (float*)d_out;

  char* ws = (char*)d_ws;
  const size_t xw_bytes = (size_t)NB * TSEQ * QDIM * sizeof(float);   // 8 MB
  float* xw = (float*)ws;
  void* bwd = (void*)(ws + xw_bytes);
  const size_t need_f32 = xw_bytes + (size_t)NB * TSEQ * HID * sizeof(float);  // 72 MB
  const bool f32ws = (ws_size >= need_f32);

  xw_kernel<<<(NB * TSEQ) / 16, 256, 0, stream>>>(x, W_in, b_in, xw);

  if (f32ws) {
    qbigru_main<false><<<256, 64, 0, stream>>>(W_in, W_out, b_out,
        thr_f, thr1_f, thu_f, thr_b, thr1_b, thu_b, xw, out, bwd);
  } else {
    qbigru_main<true><<<256, 64, 0, stream>>>(W_in, W_out, b_out,
        thr_f, thr1_f, thu_f, thr_b, thr1_b, thu_b, xw, out, bwd);
  }

  const long n4 = (long)NB * TSEQ * HID / 4;
  if (f32ws) combine_k<false><<<2048, 256, 0, stream>>>(out, bwd, n4);
  else       combine_k<true><<<2048, 256, 0, stream>>>(out, bwd, n4);
}

// Round 2
// 929.598 us; speedup vs baseline: 1.1201x; 1.1201x over previous
//
#include <hip/hip_runtime.h>
#include <hip/hip_bf16.h>

#define TSEQ 1024
#define NB   128
#define HID  128
#define QDIM 16

typedef unsigned int  u32;
typedef unsigned short u16;
typedef float f32x2 __attribute__((ext_vector_type(2)));

// ---------------- cross-lane helpers (wave64) ----------------

template<int CTRL>
__device__ __forceinline__ int dpp_i(int x) {
  return __builtin_amdgcn_update_dpp(0, x, CTRL, 0xF, 0xF, true);
}
template<int CTRL>
__device__ __forceinline__ float dpp_f(float x) {
  return __int_as_float(dpp_i<CTRL>(__float_as_int(x)));
}

#ifdef __has_builtin
#if __has_builtin(__builtin_amdgcn_permlane16_swap) && __has_builtin(__builtin_amdgcn_permlane32_swap)
#define HAS_PLS 1
#endif
#endif
#ifndef HAS_PLS
#define HAS_PLS 0
#endif

// x + x[lane^16]
__device__ __forceinline__ float pls16_sum(float x) {
#if HAS_PLS
  auto r = __builtin_amdgcn_permlane16_swap(__float_as_uint(x), __float_as_uint(x), false, false);
  return __uint_as_float(r[0]) + __uint_as_float(r[1]);
#else
  return x + __shfl_xor(x, 16, 64);
#endif
}
// x + x[lane^32]
__device__ __forceinline__ float pls32_sum(float x) {
#if HAS_PLS
  auto r = __builtin_amdgcn_permlane32_swap(__float_as_uint(x), __float_as_uint(x), false, false);
  return __uint_as_float(r[0]) + __uint_as_float(r[1]);
#else
  return x + __shfl_xor(x, 32, 64);
#endif
}
__device__ __forceinline__ float pls32_other(float x) { return pls32_sum(x) - x; }

__device__ __forceinline__ float rcpf(float x) { return __builtin_amdgcn_rcpf(x); }

__device__ __forceinline__ float ex2(float x) {
#if defined(__has_builtin)
#if __has_builtin(__builtin_amdgcn_exp2f)
  return __builtin_amdgcn_exp2f(x);
#else
  return exp2f(x);
#endif
#else
  return exp2f(x);
#endif
}

__device__ __forceinline__ u16 f2bf(float f) {
  u32 u = __float_as_uint(f);
  u32 r = (u + 0x7FFFu + ((u >> 16) & 1u)) >> 16;
  return (u16)r;
}

// CNOT-ladder index map g (same chain as the verified R1 kernel's sinv build):
// new matvec output slot j holds y[g(j)]  <=>  old amp[s] = sum_j U[s,sinv[j]] y[j].
__device__ __forceinline__ int gperm(int t) {
  int u = t;
#define APPLY(c, tt) u ^= (((u >> (3 - (c))) & 1) << (3 - (tt)));
  APPLY(3, 1) APPLY(2, 0) APPLY(1, 3) APPLY(0, 2)
  APPLY(3, 0) APPLY(2, 3) APPLY(1, 2) APPLY(0, 1)
#undef APPLY
  return u;
}

// ---------------- kernel 1: xwP[b,t,j] = x[b,t,:] @ W_x[:,g(j)] + b_in[g(j)] ----------------

__global__ __launch_bounds__(256) void xw_kernel(
    const float* __restrict__ x, const float* __restrict__ W_in,
    const float* __restrict__ b_in, float* __restrict__ xw) {
  __shared__ __align__(16) float xs[16][132];
  __shared__ float wl[2048];
  __shared__ float bl[16];
  const int tid = threadIdx.x;
  const long r0 = (long)blockIdx.x * 16;
#pragma unroll
  for (int i = 0; i < 8; ++i) {
    int idx = tid + i * 256;
    xs[idx >> 7][idx & 127] = x[(r0 + (idx >> 7)) * 128 + (idx & 127)];
  }
#pragma unroll
  for (int i = 0; i < 8; ++i) {
    int idx = tid + i * 256;
    wl[idx] = W_in[2048 + idx];   // W_x = W_in[128:256, :]
  }
  if (tid < 16) bl[tid] = b_in[tid];
  __syncthreads();
  const int rr = tid >> 4, j = tid & 15;
  const int gj = gperm(j);
  float s = bl[gj];
#pragma unroll
  for (int k4 = 0; k4 < 32; ++k4) {
    float4 v = *reinterpret_cast<const float4*>(&xs[rr][k4 * 4]);
    int kb = k4 * 4;
    s = fmaf(v.x, wl[(kb + 0) * 16 + gj], s);
    s = fmaf(v.y, wl[(kb + 1) * 16 + gj], s);
    s = fmaf(v.z, wl[(kb + 2) * 16 + gj], s);
    s = fmaf(v.w, wl[(kb + 3) * 16 + gj], s);
  }
  xw[(r0 + rr) * 16 + j] = s;
}

// ---------------- kernel 2: recurrence. 256 blocks x 1 wave; all-register ----------------

template<bool BF16WS>
__global__ __launch_bounds__(64, 1) void qbigru_main(
    const float* __restrict__ W_in,
    const float* __restrict__ W_out,
    const float* __restrict__ b_out,
    const float* __restrict__ thr_f, const float* __restrict__ thr1_f, const float* __restrict__ thu_f,
    const float* __restrict__ thr_b, const float* __restrict__ thr1_b, const float* __restrict__ thu_b,
    const float* __restrict__ xw,
    float* __restrict__ out,
    void* __restrict__ bwdws) {
  const int tid = threadIdx.x;
  const int row = tid >> 4;
  const int col = tid & 15;
  const int dir = blockIdx.x >> 7;
  const int b   = blockIdx.x & 127;
  const int l0 = tid & 1, l1 = (tid >> 1) & 1, l2b = (tid >> 2) & 1, l3 = (tid >> 3) & 1;
  const bool lt2 = (row < 2);

  // xor4-within-row via row_shl:4 / row_shr:4 + probe-derived select (convention-proof).
  const int pshl = dpp_i<0x104>(tid);
  const int sel4 = (pshl == (tid ^ 4)) ? ~0 : 0;
  auto xor4f = [&](float x) {
    int a = dpp_i<0x104>(__float_as_int(x));
    int c = dpp_i<0x114>(__float_as_int(x));
    return __int_as_float((a & sel4) | (c & ~sel4));
  };

  // reduce-scatter: v[0..15] per lane -> full 64-lane sum of v[*][l&15], replicated.
  auto bfr = [&](const float* v) -> float {
    float w1[8];
#pragma unroll
    for (int i = 0; i < 8; ++i) {
      float send = l0 ? v[2 * i] : v[2 * i + 1];
      float keep = l0 ? v[2 * i + 1] : v[2 * i];
      w1[i] = keep + dpp_f<0xB1>(send);
    }
    float w2[4];
#pragma unroll
    for (int i = 0; i < 4; ++i) {
      float send = l1 ? w1[2 * i] : w1[2 * i + 1];
      float keep = l1 ? w1[2 * i + 1] : w1[2 * i];
      w2[i] = keep + dpp_f<0x4E>(send);
    }
    float w3[2];
#pragma unroll
    for (int i = 0; i < 2; ++i) {
      float send = l3 ? w2[i] : w2[i + 2];
      float keep = l3 ? w2[i + 2] : w2[i];
      w3[i] = keep + dpp_f<0x128>(send);
    }
    float send = l2b ? w3[0] : w3[1];
    float keep = l2b ? w3[1] : w3[0];
    float y0 = keep + xor4f(send);
    return pls32_sum(pls16_sum(y0));
  };

  // +/- butterfly over the 16-lane row: eb[B](l) = (-1)^{l_B} * sum_s p[s]*(1-2*bit_B(s));
  // sign factor folded into woP constants. Also n2 = sum_s p[s].
  auto ebf = [&](float p, float& n2, float* eb) {
    float s4 = xor4f(p);
    float P  = p + s4, M2 = p - s4;
    float dP = dpp_f<0x128>(P), dM2 = dpp_f<0x128>(M2);
    float P3 = P + dP, M3 = P - dP; M2 = M2 + dM2;
    float a1 = dpp_f<0x4E>(P3), a2 = dpp_f<0x4E>(M3), a3 = dpp_f<0x4E>(M2);
    float P1 = P3 + a1, M1 = P3 - a1; M3 += a2; M2 += a3;
    float b0_ = dpp_f<0xB1>(P1), b1_ = dpp_f<0xB1>(M1), b3_ = dpp_f<0xB1>(M3), b2_ = dpp_f<0xB1>(M2);
    n2 = P1 + b0_;
    eb[0] = P1 - b0_; eb[1] = M1 + b1_; eb[3] = M3 + b3_; eb[2] = M2 + b2_;
  };

  // ---- per-lane constants ----
  const float* thr  = dir ? thr_b  : thr_f;
  const float* thr1 = dir ? thr1_b : thr1_f;
  const float* thu  = dir ? thu_b  : thu_f;
  const float* thA  = lt2 ? thr : thu;   // rows 0,1 -> reset VQC; rows 2,3 -> update VQC
  float ch1[4], sh1[4], ns1[4], ch2[4], sh2[4], ns2[4];
#pragma unroll
  for (int i = 0; i < 4; ++i) {
    float a = 0.5f * thA[i];   ch1[i] = cosf(a);  sh1[i] = sinf(a);  ns1[i] = -sh1[i];
    float a2 = 0.5f * thr1[i]; ch2[i] = cosf(a2); sh2[i] = sinf(a2); ns2[i] = -sh2[i];
  }

  // W_h with CNOT perm folded: slot j uses column g(j). Lane handles k = tid, tid+64.
  f32x2 w0p[8], w1p[8];
#pragma unroll
  for (int i = 0; i < 8; ++i) {
    int ja = gperm(2 * i), jb = gperm(2 * i + 1);
    f32x2 a, c;
    a.x = W_in[tid * QDIM + ja];        a.y = W_in[tid * QDIM + jb];
    c.x = W_in[(tid + 64) * QDIM + ja]; c.y = W_in[(tid + 64) * QDIM + jb];
    w0p[i] = a; w1p[i] = c;
  }

  // W_out reindexed (wire w = 3-B) with e-butterfly sign correction (-1)^{l_B}.
  float woP0[4], woP1[4];
#pragma unroll
  for (int B = 0; B < 4; ++B) {
    float sgn = ((tid >> B) & 1) ? -1.f : 1.f;
    woP0[B] = W_out[(3 - B) * HID + tid] * sgn;
    woP1[B] = W_out[(3 - B) * HID + tid + 64] * sgn;
  }
  const float L2E = 1.4426950408889634f;
  const float nbc0 = -b_out[tid] * L2E;
  const float nbc1 = -b_out[tid + 64] * L2E;
  const float bc20 = b_out[tid] * (2.f * L2E);
  const float bc21 = b_out[tid + 64] * (2.f * L2E);

  auto dot4 = [](const float* e, const float* w) {
    return fmaf(e[1], w[1], e[0] * w[0]) + fmaf(e[3], w[3], e[2] * w[2]);
  };

  // RX stage: Re' = ch*Re + sh*Im_p ; Im' = ch*Im - sh*Re_p  (p = partner at distance d)
#define MVSTAGE(SHUF, CH, SH, NS)  { float Rp = SHUF(Re), Ip = SHUF(Im); \
    Re = fmaf((CH), Re, (SH) * Ip); Im = fmaf((CH), Im, (NS) * Rp); }

  float h0 = 0.f, h1 = 0.f;
  const float* pxw = xw + ((long)b * TSEQ + (dir ? TSEQ - 1 : 0)) * QDIM;
  const long xstep = dir ? -QDIM : QDIM;
  float xc = pxw[col]; pxw += xstep;
  float xn = pxw[col]; pxw += xstep;

  float* po  = out + (long)b * TSEQ * HID + tid;
  float* pbf = (float*)bwdws + (long)b * TSEQ * HID + tid;
  u16*   pbh = (u16*)bwdws + (long)b * TSEQ * HID + tid;

#pragma unroll 1
  for (int t = 0; t < TSEQ; ++t) {
    float xnn = pxw[col]; pxw += xstep;   // prefetch t+2 (ws padded; overrun harmless)

    // ---- y = h @ W_h (permuted cols) + xwP ----
    f32x2 hh0; hh0.x = h0; hh0.y = h0;
    f32x2 hh1; hh1.x = h1; hh1.y = h1;
    float v[16];
#pragma unroll
    for (int i = 0; i < 8; ++i) {
      f32x2 a = hh0 * w0p[i] + hh1 * w1p[i];
      v[2 * i] = a.x; v[2 * i + 1] = a.y;
    }
    float yv = bfr(v) + xc;

    // ---- VQC1: 4 RX stages on lane-local complex amp (qubit1/d=4 first, Im==0) ----
    float Re = ch1[1] * yv;
    float Im = ns1[1] * xor4f(yv);
    MVSTAGE(dpp_f<0x128>, ch1[0], sh1[0], ns1[0])   // qubit0, d=8
    MVSTAGE(dpp_f<0x4E>,  ch1[2], sh1[2], ns1[2])   // qubit2, d=2
    MVSTAGE(dpp_f<0xB1>,  ch1[3], sh1[3], ns1[3])   // qubit3, d=1
    float prb = fmaf(Re, Re, Im * Im);              // probs_raw[col] (own VQC)

    float n2, eb[4];
    ebf(prb, n2, eb);
    float inv = rcpf(n2);
    float eo[4];
#pragma unroll
    for (int B = 0; B < 4; ++B) eo[B] = pls32_other(eb[B]);

    float dO0 = dot4(eb, woP0), dO1 = dot4(eb, woP1);
    float dX0 = dot4(eo, woP0), dX1 = dot4(eo, woP1);
    float rd0 = lt2 ? dO0 : dX0, rd1 = lt2 ? dO1 : dX1;
    float zd0 = lt2 ? dX0 : dO0, zd1 = lt2 ? dX1 : dO1;

    float nic = inv * (-L2E);
    float r0 = rcpf(1.f + ex2(fmaf(rd0, nic, nbc0)));
    float r1 = rcpf(1.f + ex2(fmaf(rd1, nic, nbc1)));
    float z0 = rcpf(1.f + ex2(fmaf(zd0, nic, nbc0)));
    float z1 = rcpf(1.f + ex2(fmaf(zd1, nic, nbc1)));

    // ---- v1 = (r*h) @ W_h + xwP ----
    float rh0 = r0 * h0, rh1 = r1 * h1;
    hh0.x = rh0; hh0.y = rh0;
    hh1.x = rh1; hh1.y = rh1;
#pragma unroll
    for (int i = 0; i < 8; ++i) {
      f32x2 a = hh0 * w0p[i] + hh1 * w1p[i];
      v[2 * i] = a.x; v[2 * i + 1] = a.y;
    }
    float vv = bfr(v) + xc;

    float Re2 = ch2[1] * vv;
    float Im2 = ns2[1] * xor4f(vv);
    { float& Re = Re2; float& Im = Im2;
      MVSTAGE(dpp_f<0x128>, ch2[0], sh2[0], ns2[0])
      MVSTAGE(dpp_f<0x4E>,  ch2[2], sh2[2], ns2[2])
      MVSTAGE(dpp_f<0xB1>,  ch2[3], sh2[3], ns2[3])
    }
    float prb2 = fmaf(Re2, Re2, Im2 * Im2);

    float n2b, eb2[4];
    ebf(prb2, n2b, eb2);
    float invb = rcpf(n2b);
    float hd0 = dot4(eb2, woP0), hd1 = dot4(eb2, woP1);

    float i2c = invb * (2.f * L2E);
    float h20 = fmaf(-2.f, rcpf(1.f + ex2(fmaf(hd0, i2c, bc20))), 1.f);
    float h21 = fmaf(-2.f, rcpf(1.f + ex2(fmaf(hd1, i2c, bc21))), 1.f);

    float hn0 = fmaf(z0, h20 - h0, h0);
    float hn1 = fmaf(z1, h21 - h1, h1);

    if (dir == 0) {
      po[0]  = 0.5f * hn0;
      po[64] = 0.5f * hn1;
      po += HID;
    } else if (BF16WS) {
      pbh[0]  = f2bf(0.5f * hn0);
      pbh[64] = f2bf(0.5f * hn1);
      pbh += HID;
    } else {
      pbf[0]  = 0.5f * hn0;
      pbf[64] = 0.5f * hn1;
      pbf += HID;
    }

    h0 = hn0; h1 = hn1;
    xc = xn; xn = xnn;
  }
#undef MVSTAGE
}

// ---------------- kernel 3: out += bwd trajectory ----------------

template<bool BF16WS>
__global__ __launch_bounds__(256) void combine_k(float* __restrict__ out,
                                                 const void* __restrict__ bwd, long n4) {
  long i = (long)blockIdx.x * 256 + threadIdx.x;
  const long stride = (long)gridDim.x * 256;
  for (; i < n4; i += stride) {
    float4 o = reinterpret_cast<float4*>(out)[i];
    float ax, ay, az, aw;
    if (BF16WS) {
      ushort4 u = reinterpret_cast<const ushort4*>(bwd)[i];
      ax = __uint_as_float((u32)u.x << 16);
      ay = __uint_as_float((u32)u.y << 16);
      az = __uint_as_float((u32)u.z << 16);
      aw = __uint_as_float((u32)u.w << 16);
    } else {
      float4 a = reinterpret_cast<const float4*>(bwd)[i];
      ax = a.x; ay = a.y; az = a.z; aw = a.w;
    }
    o.x += ax; o.y += ay; o.z += az; o.w += aw;
    reinterpret_cast<float4*>(out)[i] = o;
  }
}

// ---------------- launch ----------------

extern "C" void kernel_launch(void* const* d_in, const int* in_sizes, int n_in,
                              void* d_out, int out_size, void* d_ws, size_t ws_size,
                              hipStream_t stream) {
  const float* x     = (const float*)d_in[0];
  const float* W_in  = (const float*)d_in[1];
  const float* b_in  = (const float*)d_in[2];
  const float* W_out = (const float*)d_in[3];
  const float* b_out = (const float*)d_in[4];
  const float* thr_f  = (const float*)d_in[5];
  const float* thr1_f = (const float*)d_in[6];
  const float* thu_f  = (const float*)d_in[7];
  const float* thr_b  = (const float*)d_in[8];
  const float* thr1_b = (const float*)d_in[9];
  const float* thu_b  = (const float*)d_in[10];
  float* out = (float*)d_out;

  char* ws = (char*)d_ws;
  const size_t PAD = 4096;   // xw prefetch over/under-run guard
  const size_t xw_bytes = (size_t)NB * TSEQ * QDIM * sizeof(float);   // 8 MB
  float* xw = (float*)(ws + PAD);
  void* bwd = (void*)(ws + PAD + xw_bytes + PAD);
  const size_t need_f32 = 2 * PAD + xw_bytes + (size_t)NB * TSEQ * HID * sizeof(float);
  const bool f32ws = (ws_size >= need_f32);

  xw_kernel<<<(NB * TSEQ) / 16, 256, 0, stream>>>(x, W_in, b_in, xw);

  if (f32ws) {
    qbigru_main<false><<<256, 64, 0, stream>>>(W_in, W_out, b_out,
        thr_f, thr1_f, thu_f, thr_b, thr1_b, thu_b, xw, out, bwd);
  } else {
    qbigru_main<true><<<256, 64, 0, stream>>>(W_in, W_out, b_out,
        thr_f, thr1_f, thu_f, thr_b, thr1_b, thu_b, xw, out, bwd);
  }

  const long n4 = (long)NB * TSEQ * HID / 4;
  if (f32ws) combine_k<false><<<2048, 256, 0, stream>>>(out, bwd, n4);
  else       combine_k<true><<<2048, 256, 0, stream>>>(out, bwd, n4);
}